// Round 1
// 90.622 us; speedup vs baseline: 1.0535x; 1.0535x over previous
//
#include <hip/hip_runtime.h>

// BSpline evaluation, MI355X.
// t [2048] f32 sorted, c [512,2048] f32, delta [1] i32.
// out = sample_points [S] ++ spline_values [S, DIM]; S=32768, DIM=512.
// R5: single fused kernel. Previous 2-kernel version handed 4.7+ MB of
// just-written intermediates (cT/jbuf/bbuf) across XCDs -> dirty-L2
// coherence misses throttled eval to ~1.5 TB/s. Now each block:
//   phase 1: 128 samples' span search + Cox-de Boor weights -> LDS
//   phase 2: stage the block's needed c columns (typ. ~12-16, cap 64)
//            into LDS, transposed (global reads stay row-contiguous)
//   phase 3: out[s][d] = sum_m b[m] * c[d][j-3+m], nontemporal stores.
// Zero intermediate global traffic; d_ws unused.

#define DEG 3
#define SBLK 128            // samples per block
#define DBLK 128            // dims per block
#define NCOLS 64            // LDS capacity for staged c columns (pow2)
#define CSTRIDE (DBLK + 4)  // 132: rows stay 16B-aligned (528 B), kills 32-way write conflict

typedef float vfloat4 __attribute__((ext_vector_type(4)));

__device__ __forceinline__ float kn(const float* __restrict__ t, int i) {
    return (i < DEG + 1) ? 0.0f : t[i - (DEG + 1)];
}

__global__ __launch_bounds__(256) void bspline_fused(
    const float* __restrict__ t, const float* __restrict__ c,
    const int* __restrict__ delta_p, float* __restrict__ out_pts,
    vfloat4* __restrict__ out_spline, int S, int NK, int DIM, int nd)
{
    __shared__ __attribute__((aligned(16))) float lc[NCOLS][CSTRIDE];
    __shared__ vfloat4 bwS[SBLK];
    __shared__ int jS[SBLK];

    const int tid = threadIdx.x;
    const int dchunk = blockIdx.x % nd;
    const int sb = blockIdx.x / nd;
    const int s0 = sb * SBLK;
    const int dbase = dchunk * DBLK;

    // ---- phase 1: span search + weight triangle (threads 0..SBLK-1) ----
    if (tid < SBLK) {
        const int s = s0 + tid;
        const int sc = (s < S) ? s : (S - 1);
        const float delta = (float)(*delta_p);
        const float sv = (float)sc * delta;
        if (dchunk == 0 && s < S) out_pts[s] = sv;

        // rightmost j in [DEG, NK+DEG-1] with kn(j) <= sv
        int lo = DEG, hi = NK + DEG - 1;
        while (lo < hi) {
            int mid = (lo + hi + 1) >> 1;
            if (kn(t, mid) <= sv) lo = mid; else hi = mid - 1;
        }
        int j = lo;
        vfloat4 b4 = (vfloat4){0.f, 0.f, 0.f, 0.f};
        if (j < NK) {
            // Cox-de Boor triangle: N[d][k] = val(j-d+k, d), where(denom==0 -> 0)
            float N[DEG + 1][DEG + 1];
            N[0][0] = 1.0f;
            #pragma unroll
            for (int d = 1; d <= DEG; ++d) {
                #pragma unroll
                for (int k = 0; k <= d; ++k) {
                    int i = j - d + k;
                    float vpi  = (k >= 1) ? N[d - 1][k - 1] : 0.0f;
                    float vpi1 = (k <= d - 1) ? N[d - 1][k] : 0.0f;
                    float ki   = kn(t, i);
                    float kid  = kn(t, i + d);
                    float ki1  = kn(t, i + 1);
                    float kid1 = kn(t, i + d + 1);
                    float den1 = kid - ki;
                    float den2 = kid1 - ki1;
                    float w1 = (den1 != 0.0f) ? (sv - ki) / den1 : 0.0f;
                    float w2 = (den2 != 0.0f) ? (kid1 - sv) / den2 : 0.0f;
                    N[d][k] = w1 * vpi + w2 * vpi1;
                }
            }
            // stale-column quirk: col i keeps degree min(DEG, NK-1-i)
            float b[DEG + 1];
            #pragma unroll
            for (int m = 0; m <= DEG; ++m) {
                int col = j - DEG + m;
                int deg = NK - 1 - col; if (deg > DEG) deg = DEG;
                int idx = m - DEG + deg;
                b[m] = (idx >= 0) ? N[deg][idx] : 0.0f;
            }
            b4 = (vfloat4){b[0], b[1], b[2], b[3]};
        } else {
            j = NK - 1;   // beyond last span: zero row; clamp for col math
        }
        jS[tid] = j;
        bwS[tid] = b4;
    }
    __syncthreads();

    // ---- phase 2: stage c[dbase..+DBLK) x [colmin..colmax] -> LDS, transposed
    const int colmin = jS[0] - DEG;             // j monotone in s => >= 0
    int nc = jS[SBLK - 1] - colmin + 1;         // actual cols needed
    if (nc > NCOLS) nc = NCOLS;                 // overflow -> fallback path covers
    int ncr = 16, lsh = 4;                      // round up to pow2 (16/32/64)
    while (ncr < nc) { ncr <<= 1; ++lsh; }
    for (int e = tid; e < ncr * DBLK; e += 256) {
        int cc = e & (ncr - 1);                 // consecutive lanes = consecutive cols
        int dd = e >> lsh;
        int col = colmin + cc;
        if (col > NK - 1) col = NK - 1;         // clamped junk never read (b=0 or unused)
        lc[cc][dd] = c[(size_t)(dbase + dd) * NK + col];
    }
    __syncthreads();

    // ---- phase 3: compute + streaming store ----
    const int nv = DIM >> 2;                    // 128
    vfloat4* ob = out_spline + (size_t)s0 * nv + (dbase >> 2);
    #pragma unroll
    for (int k = 0; k < (SBLK * (DBLK >> 2)) / 256; ++k) {   // 16 iters
        const int it = k * 256 + tid;
        const int sl = it >> 5;                 // sample within block (32 float4/row-chunk)
        const int d4 = it & 31;                 // float4 index within dim chunk
        const int j = jS[sl];                   // broadcast LDS reads (32 lanes same addr)
        const vfloat4 b = bwS[sl];
        const int cl = j - DEG - colmin;        // local col of first tap
        vfloat4 r;
        if (cl + DEG < NCOLS) {                 // uniform; ~always true
            const float* p = &lc[cl][d4 << 2];
            vfloat4 a0 = *(const vfloat4*)(p);
            vfloat4 a1 = *(const vfloat4*)(p + CSTRIDE);
            vfloat4 a2 = *(const vfloat4*)(p + 2 * CSTRIDE);
            vfloat4 a3 = *(const vfloat4*)(p + 3 * CSTRIDE);
            r = b.x * a0 + b.y * a1 + b.z * a2 + b.w * a3;
        } else {                                // guaranteed-correct rare fallback
            float rv[4];
            #pragma unroll
            for (int q = 0; q < 4; ++q) {
                const float* cq = c + (size_t)(dbase + (d4 << 2) + q) * NK + (j - DEG);
                rv[q] = b.x * cq[0] + b.y * cq[1] + b.z * cq[2] + b.w * cq[3];
            }
            r = (vfloat4){rv[0], rv[1], rv[2], rv[3]};
        }
        if (s0 + sl < S)
            __builtin_nontemporal_store(r, ob + (size_t)sl * nv + d4);
    }
}

extern "C" void kernel_launch(void* const* d_in, const int* in_sizes, int n_in,
                              void* d_out, int out_size, void* d_ws, size_t ws_size,
                              hipStream_t stream) {
    const float* t = (const float*)d_in[0];
    const float* c = (const float*)d_in[1];
    const int* delta = (const int*)d_in[2];
    const int NK = in_sizes[0];                 // 2048
    const int DIM = in_sizes[1] / NK;           // 512
    const int S = out_size / (1 + DIM);         // 32768

    const int nd = DIM / DBLK;                  // 4
    const int nsb = (S + SBLK - 1) / SBLK;      // 256
    bspline_fused<<<nsb * nd, 256, 0, stream>>>(
        t, c, delta, (float*)d_out,
        (vfloat4*)((float*)d_out + S), S, NK, DIM, nd);
}

// Round 2
// 89.021 us; speedup vs baseline: 1.0724x; 1.0180x over previous
//
#include <hip/hip_runtime.h>

// BSpline evaluation, MI355X.
// t [2048] f32 sorted, c [512,2048] f32, delta [1] i32.
// out = sample_points [S] ++ spline_values [S, DIM]; S=32768, DIM=512.
// R6: R5 with PLAIN stores instead of __builtin_nontemporal_store.
// Evidence: R4-eval and R5-fused have totally different read structures but
// identical ~44-46 us; both share 67 MB of nt-flagged 16B stores at an
// effective ~1.5 TB/s, while the harness fill proves 6+ TB/s for plain
// cached writes (269 MB / 44.5 us, FETCH~0 => no read-allocate on full
// lines). Theory: nt bypasses L2 write-combining. Single-variable A/B vs R5.

#define DEG 3
#define SBLK 128            // samples per block
#define DBLK 128            // dims per block
#define NCOLS 64            // LDS capacity for staged c columns (pow2)
#define CSTRIDE (DBLK + 4)  // 132: rows stay 16B-aligned (528 B), kills 32-way write conflict

typedef float vfloat4 __attribute__((ext_vector_type(4)));

__device__ __forceinline__ float kn(const float* __restrict__ t, int i) {
    return (i < DEG + 1) ? 0.0f : t[i - (DEG + 1)];
}

__global__ __launch_bounds__(256) void bspline_fused(
    const float* __restrict__ t, const float* __restrict__ c,
    const int* __restrict__ delta_p, float* __restrict__ out_pts,
    vfloat4* __restrict__ out_spline, int S, int NK, int DIM, int nd)
{
    __shared__ __attribute__((aligned(16))) float lc[NCOLS][CSTRIDE];
    __shared__ vfloat4 bwS[SBLK];
    __shared__ int jS[SBLK];

    const int tid = threadIdx.x;
    const int dchunk = blockIdx.x % nd;
    const int sb = blockIdx.x / nd;
    const int s0 = sb * SBLK;
    const int dbase = dchunk * DBLK;

    // ---- phase 1: span search + weight triangle (threads 0..SBLK-1) ----
    if (tid < SBLK) {
        const int s = s0 + tid;
        const int sc = (s < S) ? s : (S - 1);
        const float delta = (float)(*delta_p);
        const float sv = (float)sc * delta;
        if (dchunk == 0 && s < S) out_pts[s] = sv;

        // rightmost j in [DEG, NK+DEG-1] with kn(j) <= sv
        int lo = DEG, hi = NK + DEG - 1;
        while (lo < hi) {
            int mid = (lo + hi + 1) >> 1;
            if (kn(t, mid) <= sv) lo = mid; else hi = mid - 1;
        }
        int j = lo;
        vfloat4 b4 = (vfloat4){0.f, 0.f, 0.f, 0.f};
        if (j < NK) {
            // Cox-de Boor triangle: N[d][k] = val(j-d+k, d), where(denom==0 -> 0)
            float N[DEG + 1][DEG + 1];
            N[0][0] = 1.0f;
            #pragma unroll
            for (int d = 1; d <= DEG; ++d) {
                #pragma unroll
                for (int k = 0; k <= d; ++k) {
                    int i = j - d + k;
                    float vpi  = (k >= 1) ? N[d - 1][k - 1] : 0.0f;
                    float vpi1 = (k <= d - 1) ? N[d - 1][k] : 0.0f;
                    float ki   = kn(t, i);
                    float kid  = kn(t, i + d);
                    float ki1  = kn(t, i + 1);
                    float kid1 = kn(t, i + d + 1);
                    float den1 = kid - ki;
                    float den2 = kid1 - ki1;
                    float w1 = (den1 != 0.0f) ? (sv - ki) / den1 : 0.0f;
                    float w2 = (den2 != 0.0f) ? (kid1 - sv) / den2 : 0.0f;
                    N[d][k] = w1 * vpi + w2 * vpi1;
                }
            }
            // stale-column quirk: col i keeps degree min(DEG, NK-1-i)
            float b[DEG + 1];
            #pragma unroll
            for (int m = 0; m <= DEG; ++m) {
                int col = j - DEG + m;
                int deg = NK - 1 - col; if (deg > DEG) deg = DEG;
                int idx = m - DEG + deg;
                b[m] = (idx >= 0) ? N[deg][idx] : 0.0f;
            }
            b4 = (vfloat4){b[0], b[1], b[2], b[3]};
        } else {
            j = NK - 1;   // beyond last span: zero row; clamp for col math
        }
        jS[tid] = j;
        bwS[tid] = b4;
    }
    __syncthreads();

    // ---- phase 2: stage c[dbase..+DBLK) x [colmin..colmax] -> LDS, transposed
    const int colmin = jS[0] - DEG;             // j monotone in s => >= 0
    int nc = jS[SBLK - 1] - colmin + 1;         // actual cols needed
    if (nc > NCOLS) nc = NCOLS;                 // overflow -> fallback path covers
    int ncr = 16, lsh = 4;                      // round up to pow2 (16/32/64)
    while (ncr < nc) { ncr <<= 1; ++lsh; }
    for (int e = tid; e < ncr * DBLK; e += 256) {
        int cc = e & (ncr - 1);                 // consecutive lanes = consecutive cols
        int dd = e >> lsh;
        int col = colmin + cc;
        if (col > NK - 1) col = NK - 1;         // clamped junk never read (b=0 or unused)
        lc[cc][dd] = c[(size_t)(dbase + dd) * NK + col];
    }
    __syncthreads();

    // ---- phase 3: compute + streaming store (plain, L2 write-back) ----
    const int nv = DIM >> 2;                    // 128
    vfloat4* ob = out_spline + (size_t)s0 * nv + (dbase >> 2);
    #pragma unroll
    for (int k = 0; k < (SBLK * (DBLK >> 2)) / 256; ++k) {   // 16 iters
        const int it = k * 256 + tid;
        const int sl = it >> 5;                 // sample within block (32 float4/row-chunk)
        const int d4 = it & 31;                 // float4 index within dim chunk
        const int j = jS[sl];                   // broadcast LDS reads (32 lanes same addr)
        const vfloat4 b = bwS[sl];
        const int cl = j - DEG - colmin;        // local col of first tap
        vfloat4 r;
        if (cl + DEG < NCOLS) {                 // uniform; ~always true
            const float* p = &lc[cl][d4 << 2];
            vfloat4 a0 = *(const vfloat4*)(p);
            vfloat4 a1 = *(const vfloat4*)(p + CSTRIDE);
            vfloat4 a2 = *(const vfloat4*)(p + 2 * CSTRIDE);
            vfloat4 a3 = *(const vfloat4*)(p + 3 * CSTRIDE);
            r = b.x * a0 + b.y * a1 + b.z * a2 + b.w * a3;
        } else {                                // guaranteed-correct rare fallback
            float rv[4];
            #pragma unroll
            for (int q = 0; q < 4; ++q) {
                const float* cq = c + (size_t)(dbase + (d4 << 2) + q) * NK + (j - DEG);
                rv[q] = b.x * cq[0] + b.y * cq[1] + b.z * cq[2] + b.w * cq[3];
            }
            r = (vfloat4){rv[0], rv[1], rv[2], rv[3]};
        }
        if (s0 + sl < S)
            ob[(size_t)sl * nv + d4] = r;
    }
}

extern "C" void kernel_launch(void* const* d_in, const int* in_sizes, int n_in,
                              void* d_out, int out_size, void* d_ws, size_t ws_size,
                              hipStream_t stream) {
    const float* t = (const float*)d_in[0];
    const float* c = (const float*)d_in[1];
    const int* delta = (const int*)d_in[2];
    const int NK = in_sizes[0];                 // 2048
    const int DIM = in_sizes[1] / NK;           // 512
    const int S = out_size / (1 + DIM);         // 32768

    const int nd = DIM / DBLK;                  // 4
    const int nsb = (S + SBLK - 1) / SBLK;      // 256
    bspline_fused<<<nsb * nd, 256, 0, stream>>>(
        t, c, delta, (float*)d_out,
        (vfloat4*)((float*)d_out + S), S, NK, DIM, nd);
}